// Round 12
// baseline (2268.369 us; speedup 1.0000x reference)
//
#include <hip/hip_runtime.h>
#include <math.h>
#include <float.h>

#define NUM_CB 8
#define CB_SIZE 256
#define DIM 128
#define BT (16 * 16384)                  // 262144 tokens
#define Q_ELEMS ((size_t)BT * DIM)       // 33554432
#define I_ELEMS ((size_t)BT * NUM_CB)    // 2097152

// Pass-A ambiguity margin (validated rounds 6-11). Do not shrink.
#define MARGIN_A 1.5e-4f

typedef short  bf16x8 __attribute__((ext_vector_type(8)));
typedef float  f32x4  __attribute__((ext_vector_type(4)));

__device__ __forceinline__ unsigned short bf16_rne(float f) {
    unsigned int u = __float_as_uint(f);
    u = u + 0x7FFFu + ((u >> 16) & 1u);
    return (unsigned short)(u >> 16);
}
__device__ __forceinline__ float bf16_tof(unsigned short h) {
    return __uint_as_float(((unsigned int)h) << 16);
}

// ---------------------------------------------------------------------------
// VALIDATED np emulation (rounds 6-11): pairwise-8 sum-of-squares, no FMA.
// ---------------------------------------------------------------------------
__device__ __forceinline__ float np_sum_sq_128(const float* a) {
#pragma clang fp contract(off)
    float r0 = 0.f, r1 = 0.f, r2 = 0.f, r3 = 0.f,
          r4 = 0.f, r5 = 0.f, r6 = 0.f, r7 = 0.f;
#pragma unroll
    for (int i = 0; i < DIM; i += 8) {
        r0 = r0 + a[i + 0] * a[i + 0];
        r1 = r1 + a[i + 1] * a[i + 1];
        r2 = r2 + a[i + 2] * a[i + 2];
        r3 = r3 + a[i + 3] * a[i + 3];
        r4 = r4 + a[i + 4] * a[i + 4];
        r5 = r5 + a[i + 5] * a[i + 5];
        r6 = r6 + a[i + 6] * a[i + 6];
        r7 = r7 + a[i + 7] * a[i + 7];
    }
    return ((r0 + r1) + (r2 + r3)) + ((r4 + r5) + (r6 + r7));
}

__global__ void rvq_esq_kernel(const float* __restrict__ cb,
                               float* __restrict__ esq) {
    int i = blockIdx.x * blockDim.x + threadIdx.x;   // 0 .. 2047
    if (i >= NUM_CB * CB_SIZE) return;
    esq[i] = np_sum_sq_128(cb + (size_t)i * DIM);
}

// esq packed: esq_pk[((k*4+m4)*64+lane)*4+j] = esq[k][16*(4*m4+j)+(lane&15)]
__global__ void rvq_esqpk_kernel(const float* __restrict__ esq,
                                 float* __restrict__ esq_pk) {
    int idx = blockIdx.x * blockDim.x + threadIdx.x;   // 0 .. 8191
    if (idx >= NUM_CB * 4 * 64 * 4) return;
    int j    = idx & 3;
    int lane = (idx >> 2) & 63;
    int m4   = (idx >> 8) & 3;
    int k    = idx >> 10;
    esq_pk[idx] = esq[k * CB_SIZE + 16 * (4 * m4 + j) + (lane & 15)];
}

// Transposed f32 codebook for coalesced Pass-B reads: cbT[k][d][c]
__global__ void rvq_transpose_kernel(const float* __restrict__ cb,
                                     float* __restrict__ cbT) {
    int idx = blockIdx.x * blockDim.x + threadIdx.x;   // 0 .. 262143
    if (idx >= NUM_CB * DIM * CB_SIZE) return;
    int c = idx & (CB_SIZE - 1);
    int d = (idx >> 8) & (DIM - 1);
    int k = idx >> 15;
    cbT[idx] = cb[((size_t)(k * CB_SIZE + c)) * DIM + d];
}

// ---------------------------------------------------------------------------
// Precompute merged bf16 hi|lo image in the EXACT swizzled LDS layout
// (validated r8-r11): img[t*1024 + plane*512 + cand*16 + (slot ^ (cand&15))],
// t = k*8 + T (T-th 32-candidate tile).
// ---------------------------------------------------------------------------
__global__ void rvq_split_kernel(const float* __restrict__ cb,
                                 bf16x8* __restrict__ g_img) {
    int idx = blockIdx.x * blockDim.x + threadIdx.x;   // 0 .. 32767
    if (idx >= NUM_CB * CB_SIZE * 16) return;
    int slot = idx & 15;
    int cand = (idx >> 4) & 31;
    int t    = idx >> 9;                  // 0..63
    const float* src = cb + ((size_t)t * 32 + cand) * DIM + slot * 8;
    float4 a = *reinterpret_cast<const float4*>(src);
    float4 b = *reinterpret_cast<const float4*>(src + 4);
    float e[8] = {a.x, a.y, a.z, a.w, b.x, b.y, b.z, b.w};
    bf16x8 eh, el;
#pragma unroll
    for (int i = 0; i < 8; ++i) {
        unsigned short h = bf16_rne(e[i]);
        float rem = e[i] - bf16_tof(h);
        eh[i] = (short)h;
        el[i] = (short)bf16_rne(rem);
    }
    int ds = slot ^ (cand & 15);
    g_img[(size_t)t * 1024 + cand * 16 + ds]       = eh;
    g_img[(size_t)t * 1024 + 512 + cand * 16 + ds] = el;
}

// ---------------------------------------------------------------------------
// Per-codebook streaming step. Grid 256 x 768 threads (12 waves, 3/SIMD).
// Stage cb k's 128 KB image into LDS once; then waves independently stream
// token-groups with NO barriers. Residual lives in rq (= out_q region),
// updated in place; k=7 writes quantized = z - r_final.
// ---------------------------------------------------------------------------
__global__ __launch_bounds__(768, 3) void rvq_step_kernel(
    int k,
    const float* __restrict__ z,
    float* __restrict__ rq,
    const float* __restrict__ cb,
    const float* __restrict__ cbT,
    const float* __restrict__ esq,
    const float* __restrict__ esq_pk,
    const bf16x8* __restrict__ g_img,
    float* __restrict__ out_idx,
    double* __restrict__ loss_acc) {

    __shared__ bf16x8 s_img[8192];                    // 128 KB cb-k image
    __shared__ __align__(16) float s_rbuf[12][DIM];   // per-wave passB residual
    __shared__ float s_m1[12][16], s_m2[12][16];
    __shared__ int   s_cmin[12][16];
    __shared__ double s_wsum[12];

    const int tid  = threadIdx.x;
    const int wid  = tid >> 6;
    const int lane = tid & 63;
    const int lrow = lane & 15;
    const int lq   = lane >> 4;

    // ---- stage codebook-k image once (global_load_lds, wave-uniform) ----
    {
        const bf16x8* gk = g_img + (size_t)k * 8192;
#pragma unroll
        for (int i = 0; i < 11; ++i) {
            int idx = tid + i * 768;
            if (idx < 8192) {   // wave-uniform at the boundary (768|512)
                __builtin_amdgcn_global_load_lds(
                    (const __attribute__((address_space(1))) unsigned int*)(gk + idx),
                    (__attribute__((address_space(3))) unsigned int*)(&s_img[idx]),
                    16, 0, 0);
            }
        }
    }
    asm volatile("s_waitcnt vmcnt(0)" ::: "memory");
    __syncthreads();   // the ONLY pre-loop barrier

    const float* esqk = esq + k * CB_SIZE;
    const float* cbk  = cb  + (size_t)k * CB_SIZE * DIM;
    const float* cbTk = cbT + (size_t)k * DIM * CB_SIZE + lane;
    const float* rsrc = (k == 0) ? z : rq;

    // per-lane esq preload: esqr[ct] = esq[k][16*ct + lrow]
    float esqr[16];
    {
        const float4* ep4 = reinterpret_cast<const float4*>(esq_pk)
                            + (size_t)k * 4 * 64 + lane;
#pragma unroll
        for (int m4 = 0; m4 < 4; ++m4) {
            float4 v = ep4[m4 * 64];
            esqr[4 * m4 + 0] = v.x; esqr[4 * m4 + 1] = v.y;
            esqr[4 * m4 + 2] = v.z; esqr[4 * m4 + 3] = v.w;
        }
    }

    double lsum = 0.0;

    for (int g = wid; g < 64; g += 12) {           // wave-independent groups
        const int tokbase = blockIdx.x * 1024 + g * 16;
        const int tok = tokbase + lrow;

        // ---- load residual: r[s][i] = rsrc[tok][32s + 8lq + i] ----
        float r[4][8];
        {
            const float* rp = rsrc + (size_t)tok * DIM + 8 * lq;
#pragma unroll
            for (int s = 0; s < 4; ++s) {
                float4 a = *reinterpret_cast<const float4*>(rp + 32 * s);
                float4 b = *reinterpret_cast<const float4*>(rp + 32 * s + 4);
                r[s][0] = a.x; r[s][1] = a.y; r[s][2] = a.z; r[s][3] = a.w;
                r[s][4] = b.x; r[s][5] = b.y; r[s][6] = b.z; r[s][7] = b.w;
            }
        }

        // ---- bf16 hi/mid split ----
        bf16x8 ah[4], am[4];
#pragma unroll
        for (int s = 0; s < 4; ++s)
#pragma unroll
            for (int i = 0; i < 8; ++i) {
                unsigned short h = bf16_rne(r[s][i]);
                float rem = r[s][i] - bf16_tof(h);
                ah[s][i] = (short)h;
                am[s][i] = (short)bf16_rne(rem);
            }

        float m1[4], m2[4];
        int   i1[4];
#pragma unroll
        for (int j = 0; j < 4; ++j) { m1[j] = FLT_MAX; m2[j] = FLT_MAX; i1[j] = 0x7fffffff; }

        // ---- Pass A: 16 column tiles x 12 MFMA ----
#pragma unroll
        for (int ct = 0; ct < 16; ++ct) {
            const int T    = ct >> 1;                 // 32-cand tile
            const int base = T * 1024 + ((ct & 1) * 16 + lrow) * 16;
            bf16x8 bh[4], bl[4];
#pragma unroll
            for (int s = 0; s < 4; ++s) {
                int ls = (4 * s + lq) ^ lrow;
                bh[s] = s_img[base + ls];
                bl[s] = s_img[base + 512 + ls];
            }
            f32x4 acc0 = {0.f, 0.f, 0.f, 0.f};
            f32x4 acc1 = {0.f, 0.f, 0.f, 0.f};
            acc0 = __builtin_amdgcn_mfma_f32_16x16x32_bf16(ah[0], bh[0], acc0, 0, 0, 0);
            acc0 = __builtin_amdgcn_mfma_f32_16x16x32_bf16(ah[1], bh[1], acc0, 0, 0, 0);
            acc1 = __builtin_amdgcn_mfma_f32_16x16x32_bf16(ah[2], bh[2], acc1, 0, 0, 0);
            acc1 = __builtin_amdgcn_mfma_f32_16x16x32_bf16(ah[3], bh[3], acc1, 0, 0, 0);
            acc0 = __builtin_amdgcn_mfma_f32_16x16x32_bf16(am[0], bh[0], acc0, 0, 0, 0);
            acc0 = __builtin_amdgcn_mfma_f32_16x16x32_bf16(am[1], bh[1], acc0, 0, 0, 0);
            acc1 = __builtin_amdgcn_mfma_f32_16x16x32_bf16(am[2], bh[2], acc1, 0, 0, 0);
            acc1 = __builtin_amdgcn_mfma_f32_16x16x32_bf16(am[3], bh[3], acc1, 0, 0, 0);
            acc0 = __builtin_amdgcn_mfma_f32_16x16x32_bf16(ah[0], bl[0], acc0, 0, 0, 0);
            acc0 = __builtin_amdgcn_mfma_f32_16x16x32_bf16(ah[1], bl[1], acc0, 0, 0, 0);
            acc1 = __builtin_amdgcn_mfma_f32_16x16x32_bf16(ah[2], bl[2], acc1, 0, 0, 0);
            acc1 = __builtin_amdgcn_mfma_f32_16x16x32_bf16(ah[3], bl[3], acc1, 0, 0, 0);

            const int c = ct * 16 + lrow;
            const float esq_c = esqr[ct];             // static index
#pragma unroll
            for (int j = 0; j < 4; ++j) {
                float s = fmaf(-2.0f, acc0[j] + acc1[j], esq_c);
                if (s < m1[j]) {
                    m2[j] = m1[j]; m1[j] = s; i1[j] = c;
                } else if (s < m2[j]) {
                    m2[j] = s;
                }
            }
        }

        // ---- cross-lane top-2 lexicographic reduce (16-lane groups) ----
#pragma unroll
        for (int d = 1; d < 16; d <<= 1) {
#pragma unroll
            for (int j = 0; j < 4; ++j) {
                float om1 = __shfl_xor(m1[j], d);
                float om2 = __shfl_xor(m2[j], d);
                int   oi1 = __shfl_xor(i1[j], d);
                bool ow = (om1 < m1[j]) || (om1 == m1[j] && oi1 < i1[j]);
                float w1 = ow ? om1 : m1[j];
                int   wi = ow ? oi1 : i1[j];
                float lo = ow ? m1[j] : om1;
                float w2 = fminf(fminf(m2[j], om2), lo);
                m1[j] = w1; i1[j] = wi; m2[j] = w2;
            }
        }
        if (lrow < 4) {
            float wm1 = lrow == 0 ? m1[0] : lrow == 1 ? m1[1] : lrow == 2 ? m1[2] : m1[3];
            float wm2 = lrow == 0 ? m2[0] : lrow == 1 ? m2[1] : lrow == 2 ? m2[2] : m2[3];
            int   wc  = lrow == 0 ? i1[0] : lrow == 1 ? i1[1] : lrow == 2 ? i1[2] : i1[3];
            int tt = 4 * lq + lrow;
            s_m1[wid][tt] = wm1;
            s_m2[wid][tt] = wm2;
            s_cmin[wid][tt] = wc;
        }
        asm volatile("s_waitcnt lgkmcnt(0)" ::: "memory");

        // ---- Pass B (rare): exact np argmin, coalesced cbT (validated) ----
        float g1 = s_m1[wid][lrow];
        float g2 = s_m2[wid][lrow];
        bool amb = (lane < 16) && !(g2 - g1 > MARGIN_A);
        unsigned long long mask = __ballot(amb);
        while (mask) {
            int srct = __ffsll(mask) - 1;
            mask &= mask - 1;
            if (lrow == srct) {
#pragma unroll
                for (int s = 0; s < 4; ++s) {
                    float4* dst = reinterpret_cast<float4*>(
                        &s_rbuf[wid][32 * s + 8 * lq]);
                    dst[0] = make_float4(r[s][0], r[s][1], r[s][2], r[s][3]);
                    dst[1] = make_float4(r[s][4], r[s][5], r[s][6], r[s][7]);
                }
            }
            asm volatile("s_waitcnt lgkmcnt(0)" ::: "memory");
            float xs = 0.f;
            if (lane == 0) xs = np_sum_sq_128(&s_rbuf[wid][0]);
            xs = __shfl(xs, 0);

            const float* rb = &s_rbuf[wid][0];
            float a0 = 0.f, a1 = 0.f, a2 = 0.f, a3 = 0.f;
#pragma unroll 8
            for (int d = 0; d < DIM; ++d) {
                float rv = rb[d];
                const float* row = cbTk + (size_t)d * CB_SIZE;
                a0 = fmaf(rv, row[0],   a0);
                a1 = fmaf(rv, row[64],  a1);
                a2 = fmaf(rv, row[128], a2);
                a3 = fmaf(rv, row[192], a3);
            }
            float dd0, dd1, dd2, dd3;
            {
#pragma clang fp contract(off)
                float S0 = xs + esqk[lane];
                float S1 = xs + esqk[lane + 64];
                float S2 = xs + esqk[lane + 128];
                float S3 = xs + esqk[lane + 192];
                dd0 = S0 - 2.0f * a0;
                dd1 = S1 - 2.0f * a1;
                dd2 = S2 - 2.0f * a2;
                dd3 = S3 - 2.0f * a3;
            }
            float bd = dd0; int bc = lane;
            if (dd1 < bd) { bd = dd1; bc = lane + 64; }
            if (dd2 < bd) { bd = dd2; bc = lane + 128; }
            if (dd3 < bd) { bd = dd3; bc = lane + 192; }
#pragma unroll
            for (int d = 1; d < 64; d <<= 1) {
                float od = __shfl_xor(bd, d);
                int   oc = __shfl_xor(bc, d);
                if (od < bd || (od == bd && oc < bc)) { bd = od; bc = oc; }
            }
            if (lane == 0) s_cmin[wid][srct] = bc;
            asm volatile("s_waitcnt lgkmcnt(0)" ::: "memory");
        }

        if (lane < 16)
            out_idx[(size_t)(tokbase + lane) * NUM_CB + k] =
                (float)s_cmin[wid][lane];

        // ---- residual update + loss ----
        const int cm = s_cmin[wid][lrow];
        const float* ep = cbk + (size_t)cm * DIM + 8 * lq;
        float l0 = 0.f, l1 = 0.f, l2 = 0.f, l3 = 0.f;
#pragma unroll
        for (int s = 0; s < 4; ++s) {
            float4 ev0 = *reinterpret_cast<const float4*>(ep + 32 * s);
            float4 ev1 = *reinterpret_cast<const float4*>(ep + 32 * s + 4);
            float d0 = ev0.x - r[s][0], d1 = ev0.y - r[s][1];
            float d2 = ev0.z - r[s][2], d3 = ev0.w - r[s][3];
            float d4 = ev1.x - r[s][4], d5 = ev1.y - r[s][5];
            float d6 = ev1.z - r[s][6], d7 = ev1.w - r[s][7];
            l0 = fmaf(d0, d0, l0); l1 = fmaf(d1, d1, l1);
            l2 = fmaf(d2, d2, l2); l3 = fmaf(d3, d3, l3);
            l0 = fmaf(d4, d4, l0); l1 = fmaf(d5, d5, l1);
            l2 = fmaf(d6, d6, l2); l3 = fmaf(d7, d7, l3);
            r[s][0] -= ev0.x; r[s][1] -= ev0.y; r[s][2] -= ev0.z; r[s][3] -= ev0.w;
            r[s][4] -= ev1.x; r[s][5] -= ev1.y; r[s][6] -= ev1.z; r[s][7] -= ev1.w;
        }
        lsum += (double)((l0 + l1) + (l2 + l3));

        // ---- store residual (k<7) or quantized = z - r_final (k==7) ----
        float* op = rq + (size_t)tok * DIM + 8 * lq;
        if (k < NUM_CB - 1) {
#pragma unroll
            for (int s = 0; s < 4; ++s) {
                *reinterpret_cast<float4*>(op + 32 * s) =
                    make_float4(r[s][0], r[s][1], r[s][2], r[s][3]);
                *reinterpret_cast<float4*>(op + 32 * s + 4) =
                    make_float4(r[s][4], r[s][5], r[s][6], r[s][7]);
            }
        } else {
            const float* zp = z + (size_t)tok * DIM + 8 * lq;
#pragma unroll
            for (int s = 0; s < 4; ++s) {
                float4 a = *reinterpret_cast<const float4*>(zp + 32 * s);
                float4 b = *reinterpret_cast<const float4*>(zp + 32 * s + 4);
                *reinterpret_cast<float4*>(op + 32 * s) =
                    make_float4(a.x - r[s][0], a.y - r[s][1],
                                a.z - r[s][2], a.w - r[s][3]);
                *reinterpret_cast<float4*>(op + 32 * s + 4) =
                    make_float4(b.x - r[s][4], b.y - r[s][5],
                                b.z - r[s][6], b.w - r[s][7]);
            }
        }
    }

    // ---- block loss reduction (one barrier + one atomic per block) ----
    for (int off = 32; off > 0; off >>= 1)
        lsum += __shfl_down(lsum, off, 64);
    if (lane == 0) s_wsum[wid] = lsum;
    __syncthreads();
    if (tid == 0) {
        double t = 0.0;
#pragma unroll
        for (int w = 0; w < 12; ++w) t += s_wsum[w];
        atomicAdd(loss_acc, t);
    }
}

__global__ void rvq_finalize_kernel(const double* __restrict__ loss_acc,
                                    float* __restrict__ out_loss) {
    out_loss[0] = (float)(1.25 * loss_acc[0] / (double)Q_ELEMS);
}

extern "C" void kernel_launch(void* const* d_in, const int* in_sizes, int n_in,
                              void* d_out, int out_size, void* d_ws, size_t ws_size,
                              hipStream_t stream) {
    const float* z  = (const float*)d_in[0];
    const float* cb = (const float*)d_in[1];

    float* out_q    = (float*)d_out;           // doubles as residual buffer
    float* out_idx  = out_q + Q_ELEMS;
    float* out_loss = out_idx + I_ELEMS;

    double* loss_acc = (double*)d_ws;
    float*  esq      = (float*)((char*)d_ws + 256);              // 8 KB
    float*  esq_pk   = (float*)((char*)d_ws + 16384);            // 32 KB
    bf16x8* g_img    = (bf16x8*)((char*)d_ws + 65536);           // 1 MB
    float*  cbT      = (float*)((char*)d_ws + 65536 + 1048576);  // 1 MB

    hipMemsetAsync(loss_acc, 0, sizeof(double), stream);
    rvq_esq_kernel<<<(NUM_CB * CB_SIZE + 255) / 256, 256, 0, stream>>>(cb, esq);
    rvq_esqpk_kernel<<<(NUM_CB * 4 * 64 * 4 + 255) / 256, 256, 0, stream>>>(
        esq, esq_pk);
    rvq_split_kernel<<<(NUM_CB * CB_SIZE * 16 + 255) / 256, 256, 0, stream>>>(
        cb, g_img);
    rvq_transpose_kernel<<<(NUM_CB * DIM * CB_SIZE + 255) / 256, 256, 0,
                           stream>>>(cb, cbT);
    for (int k = 0; k < NUM_CB; ++k) {
        rvq_step_kernel<<<256, 768, 0, stream>>>(k, z, out_q, cb, cbT, esq,
                                                 esq_pk, g_img, out_idx,
                                                 loss_acc);
    }
    rvq_finalize_kernel<<<1, 1, 0, stream>>>(loss_acc, out_loss);
}